// Round 5
// baseline (147.736 us; speedup 1.0000x reference)
//
#include <hip/hip_runtime.h>
#include <math.h>

#define A_TOT   18675      // 83*25*9
#define N_PRE   12000
#define N_POST  2000
#define IMG_X   1333.0f
#define IMG_Y   402.0f
#define MIN_SZ  16.0f
#define NMS_T   0.7f
#define NBUCK   4096       // top 12 bits of descending-order key

// ---------------- K0: zero the bucket histogram ------------------------------
__global__ void zero_kernel(uint4* __restrict__ hist4) {
    int i = threadIdx.x;                 // 256 threads * 4 uint4 = 4096 u32
#pragma unroll
    for (int e = 0; e < 4; ++e)
        hist4[e * 256 + i] = make_uint4(0u, 0u, 0u, 0u);
}

// ---------------- K1: decode -> roi, key64, bucket histogram -----------------
__global__ void decode_kernel(const float* __restrict__ anch,
                              const float* __restrict__ cls,
                              const float* __restrict__ pred,
                              float4* __restrict__ roi,
                              unsigned long long* __restrict__ key,
                              unsigned* __restrict__ hist) {
    int i = blockIdx.x * blockDim.x + threadIdx.x;
    if (i >= A_TOT) return;

    float ax1 = anch[4*i+0], ay1 = anch[4*i+1], ax2 = anch[4*i+2], ay2 = anch[4*i+3];
    float h_a  = __fsub_rn(ay2, ay1);
    float w_a  = __fsub_rn(ax2, ax1);
    float cy_a = __fadd_rn(ay1, __fmul_rn(0.5f, h_a));
    float cx_a = __fadd_rn(ax1, __fmul_rn(0.5f, w_a));

    float dx = pred[4*i+0], dy = pred[4*i+1], dw = pred[4*i+2], dh = pred[4*i+3];

    float cy = __fadd_rn(__fmul_rn(dy, h_a), cy_a);
    float cx = __fadd_rn(__fmul_rn(dx, w_a), cx_a);
    float h  = __fmul_rn(expf(dh), h_a);
    float w  = __fmul_rn(expf(dw), w_a);

    float hw = __fmul_rn(0.5f, w);
    float hh = __fmul_rn(0.5f, h);
    float x1 = fminf(fmaxf(__fsub_rn(cx, hw), 0.0f), IMG_X);
    float x2 = fminf(fmaxf(__fadd_rn(cx, hw), 0.0f), IMG_X);
    float y1 = fminf(fmaxf(__fsub_rn(cy, hh), 0.0f), IMG_Y);
    float y2 = fminf(fmaxf(__fadd_rn(cy, hh), 0.0f), IMG_Y);

    bool valid = (__fsub_rn(y2, y1) >= MIN_SZ) && (__fsub_rn(x2, x1) >= MIN_SZ);

    roi[i] = make_float4(x1, y1, x2, y2);

    float s = valid ? cls[2*i+1] : -INFINITY;
    // strictly-unique 64-bit key: ascending K == (descending score, ascending index)
    unsigned ub   = __float_as_uint(s);
    unsigned mask = ((unsigned)((int)ub >> 31)) | 0x80000000u;
    unsigned ord  = ub ^ mask;          // ascending float order
    unsigned kd   = ~ord;               // descending float order
    key[i] = ((unsigned long long)kd << 32) | (unsigned)i;
    atomicAdd(&hist[kd >> 20], 1u);
}

// ---------------- K2: exclusive scan of 4096 buckets -> bcur -----------------
// Single block, 256 threads, 16 buckets (4 uint4) each. ~32KB total traffic.
__global__ void scan_kernel(const uint4* __restrict__ hist4,
                            uint4* __restrict__ bcur4) {
    __shared__ unsigned part[256];
    const int t = threadIdx.x;
    const int base = t * 4;             // uint4 index

    uint4 v[4];
    unsigned s = 0;
#pragma unroll
    for (int e = 0; e < 4; ++e) {
        v[e] = hist4[base + e];
        s += v[e].x + v[e].y + v[e].z + v[e].w;
    }
    part[t] = s;
    __syncthreads();
    for (int off = 1; off < 256; off <<= 1) {
        unsigned x = (t >= off) ? part[t - off] : 0u;
        __syncthreads();
        part[t] += x;
        __syncthreads();
    }
    unsigned run = (t == 0) ? 0u : part[t - 1];   // exclusive base for this chunk
#pragma unroll
    for (int e = 0; e < 4; ++e) {
        uint4 o;
        o.x = run; run += v[e].x;
        o.y = run; run += v[e].y;
        o.z = run; run += v[e].z;
        o.w = run; run += v[e].w;
        bcur4[base + e] = o;
    }
}

// ---------------- K3: scatter keys into bucket-grouped array -----------------
__global__ void bucket_scatter_kernel(const unsigned long long* __restrict__ key,
                                      unsigned* __restrict__ bcur,
                                      unsigned long long* __restrict__ bkey) {
    int i = blockIdx.x * blockDim.x + threadIdx.x;
    if (i >= A_TOT) return;
    unsigned long long Ki = key[i];
    unsigned b = (unsigned)(Ki >> 52);
    unsigned pos = atomicAdd(&bcur[b], 1u);
    bkey[pos] = Ki;
}

// ---------------- K4: exact rank within bucket + scatter to sorted arrays ----
// After K3, bcur[b] = start[b] + cnt[b]; so start = bcur[b] - hist[b].
__global__ void rankscatter_kernel(const unsigned long long* __restrict__ key,
                                   const unsigned* __restrict__ hist,
                                   const unsigned* __restrict__ bcur,
                                   const unsigned long long* __restrict__ bkey,
                                   const float4* __restrict__ roi,
                                   float4* __restrict__ sboxes,
                                   float* __restrict__ sareas) {
    int i = blockIdx.x * blockDim.x + threadIdx.x;
    if (i >= A_TOT) return;
    unsigned long long Ki = key[i];
    unsigned b = (unsigned)(Ki >> 52);
    unsigned cnt   = hist[b];
    unsigned start = bcur[b] - cnt;
    if (start >= N_PRE) return;            // rank >= start: not in top-N_PRE
    unsigned r = start;
    if (cnt > 1) {
        for (unsigned m = 0; m < cnt; ++m)
            r += (bkey[start + m] < Ki) ? 1u : 0u;
    }
    if (r < N_PRE) {
        float4 bx = roi[i];
        sboxes[r] = bx;
        sareas[r] = __fmul_rn(__fadd_rn(__fsub_rn(bx.z, bx.x), 1.0f),
                              __fadd_rn(__fsub_rn(bx.w, bx.y), 1.0f));
    }
}

// ---------------- K5: diagonal pair-overlap marking --------------------------
// mark[i] = OR over z in [0, N_PRE-2-i] of IoU(b[z], b[z+i+1]) >= 0.7
__global__ void nms_kernel(const float4* __restrict__ sboxes,
                           const float* __restrict__ sareas,
                           unsigned* __restrict__ mark) {
    int wid  = (blockIdx.x * blockDim.x + threadIdx.x) >> 6;
    int lane = threadIdx.x & 63;
    if (wid >= N_PRE) return;
    const int i      = wid;
    const int npairs = N_PRE - 1 - i;   // z in [0, npairs)

    bool found = false;
    for (int base = 0; base < npairs; base += 64) {
        int z = base + lane;
        bool over = false;
        if (z < npairs) {
            float4 bz = sboxes[z];
            float4 bj = sboxes[z + i + 1];
            float az = sareas[z];
            float aj = sareas[z + i + 1];
            float xx1 = fmaxf(bz.x, bj.x);
            float yy1 = fmaxf(bz.y, bj.y);
            float xx2 = fminf(bz.z, bj.z);
            float yy2 = fminf(bz.w, bj.w);
            float w = fmaxf(0.0f, __fadd_rn(__fsub_rn(xx2, xx1), 1.0f));
            float h = fmaxf(0.0f, __fadd_rn(__fsub_rn(yy2, yy1), 1.0f));
            float inter = __fmul_rn(w, h);
            float denom = __fsub_rn(__fadd_rn(az, aj), inter);
            float ovr   = __fdiv_rn(inter, denom);
            over = (ovr >= NMS_T);
        }
        if (__any(over)) { found = true; break; }
    }
    if (lane == 0) mark[i] = found ? 1u : 0u;
}

// ---------------- K6: stable compaction + output -----------------------------
__global__ void output_kernel(const unsigned* __restrict__ mark,
                              const float4* __restrict__ sboxes,
                              float* __restrict__ out) {
    __shared__ int lds[1024];
    __shared__ int s_total;
    const int t = threadIdx.x;
    const int E = 12;                 // 1024*12 = 12288 >= 12000
    const int i0 = t * E;

    bool keep[E];
    int cnt = 0;
#pragma unroll
    for (int e = 0; e < E; ++e) {
        int i = i0 + e;
        bool k = (i < N_PRE) && (mark[i] == 0u);
        keep[e] = k;
        cnt += k ? 1 : 0;
    }
    lds[t] = cnt;
    __syncthreads();
    for (int off = 1; off < 1024; off <<= 1) {
        int x = (t >= off) ? lds[t - off] : 0;
        __syncthreads();
        lds[t] += x;
        __syncthreads();
    }
    int incl = lds[t];
    int base = incl - cnt;
    if (t == 1023) s_total = incl;
    __syncthreads();
    const int total = s_total;

    int pos = base;
#pragma unroll
    for (int e = 0; e < E; ++e) {
        if (keep[e] && pos < N_POST) {
            float4 b = sboxes[i0 + e];
            out[4*pos+0] = b.x;
            out[4*pos+1] = b.y;
            out[4*pos+2] = b.z;
            out[4*pos+3] = b.w;
            out[4*N_POST + pos] = 1.0f;
        }
        pos += keep[e] ? 1 : 0;
    }
    for (int p = t; p < N_POST; p += 1024) {
        if (p >= total) {
            out[4*p+0] = 0.0f; out[4*p+1] = 0.0f;
            out[4*p+2] = 0.0f; out[4*p+3] = 0.0f;
            out[4*N_POST + p] = 0.0f;
        }
    }
}

// ---------------- launch ------------------------------------------------------
extern "C" void kernel_launch(void* const* d_in, const int* in_sizes, int n_in,
                              void* d_out, int out_size, void* d_ws, size_t ws_size,
                              hipStream_t stream) {
    const float* anch = (const float*)d_in[0];   // (A,4)
    const float* cls  = (const float*)d_in[1];   // (1,A,2)
    const float* pred = (const float*)d_in[2];   // (1,A,4)
    float* out = (float*)d_out;                  // 8000 rois + 2000 kept

    char* ws = (char*)d_ws;
    float4*             roi    = (float4*)(ws + 0);                   // 298,800
    unsigned long long* key    = (unsigned long long*)(ws + 299008);  // 149,400
    unsigned*           hist   = (unsigned*)(ws + 448512);            //  16,384
    unsigned*           bcur   = (unsigned*)(ws + 464896);            //  16,384
    unsigned long long* bkey   = (unsigned long long*)(ws + 481280);  // 149,400
    float4*             sboxes = (float4*)(ws + 630784);              // 192,000
    float*              sareas = (float*)(ws + 822784);               //  48,000
    unsigned*           mark   = (unsigned*)(ws + 870784);            //  48,000

    const int TB = 256;
    const int ablk = (A_TOT + TB - 1) / TB;      // 73

    zero_kernel<<<1, TB, 0, stream>>>((uint4*)hist);
    decode_kernel<<<ablk, TB, 0, stream>>>(anch, cls, pred, roi, key, hist);
    scan_kernel<<<1, TB, 0, stream>>>((const uint4*)hist, (uint4*)bcur);
    bucket_scatter_kernel<<<ablk, TB, 0, stream>>>(key, bcur, bkey);
    rankscatter_kernel<<<ablk, TB, 0, stream>>>(key, hist, bcur, bkey, roi, sboxes, sareas);
    nms_kernel<<<(N_PRE * 64) / TB, TB, 0, stream>>>(sboxes, sareas, mark);
    output_kernel<<<1, 1024, 0, stream>>>(mark, sboxes, out);
}

// Round 6
// 51.800 us; speedup vs baseline: 2.8521x; 2.8521x over previous
//
#include <hip/hip_runtime.h>
#include <math.h>

#define A_TOT   18675      // 83*25*9
#define N_PRE   12000
#define N_POST  2000
#define IMG_X   1333.0f
#define IMG_Y   402.0f
#define MIN_SZ  16.0f
#define NMS_T   0.7f
#define NBUCK   4096       // top 12 bits of descending-order key

// ---------------- K1: decode -> roi, key64 -----------------------------------
__global__ void decode_kernel(const float* __restrict__ anch,
                              const float* __restrict__ cls,
                              const float* __restrict__ pred,
                              float4* __restrict__ roi,
                              unsigned long long* __restrict__ key) {
    int i = blockIdx.x * blockDim.x + threadIdx.x;
    if (i >= A_TOT) return;

    float ax1 = anch[4*i+0], ay1 = anch[4*i+1], ax2 = anch[4*i+2], ay2 = anch[4*i+3];
    float h_a  = __fsub_rn(ay2, ay1);
    float w_a  = __fsub_rn(ax2, ax1);
    float cy_a = __fadd_rn(ay1, __fmul_rn(0.5f, h_a));
    float cx_a = __fadd_rn(ax1, __fmul_rn(0.5f, w_a));

    float dx = pred[4*i+0], dy = pred[4*i+1], dw = pred[4*i+2], dh = pred[4*i+3];

    float cy = __fadd_rn(__fmul_rn(dy, h_a), cy_a);
    float cx = __fadd_rn(__fmul_rn(dx, w_a), cx_a);
    float h  = __fmul_rn(expf(dh), h_a);
    float w  = __fmul_rn(expf(dw), w_a);

    float hw = __fmul_rn(0.5f, w);
    float hh = __fmul_rn(0.5f, h);
    float x1 = fminf(fmaxf(__fsub_rn(cx, hw), 0.0f), IMG_X);
    float x2 = fminf(fmaxf(__fadd_rn(cx, hw), 0.0f), IMG_X);
    float y1 = fminf(fmaxf(__fsub_rn(cy, hh), 0.0f), IMG_Y);
    float y2 = fminf(fmaxf(__fadd_rn(cy, hh), 0.0f), IMG_Y);

    bool valid = (__fsub_rn(y2, y1) >= MIN_SZ) && (__fsub_rn(x2, x1) >= MIN_SZ);

    roi[i] = make_float4(x1, y1, x2, y2);

    float s = valid ? cls[2*i+1] : -INFINITY;
    // strictly-unique 64-bit key: ascending K == (descending score, ascending index)
    unsigned ub   = __float_as_uint(s);
    unsigned mask = ((unsigned)((int)ub >> 31)) | 0x80000000u;
    unsigned ord  = ub ^ mask;          // ascending float order
    unsigned kd   = ~ord;               // descending float order
    key[i] = ((unsigned long long)kd << 32) | (unsigned)i;
}

// ---------------- K2: fused hist + scan + bucket scatter (1 block) -----------
// LDS histogram of 4096 buckets, exclusive scan, then scatter keys into
// bucket-grouped bkey[]. Emits bstart[] and bcnt[].
__global__ __launch_bounds__(1024)
void sortprep_kernel(const unsigned long long* __restrict__ key,
                     unsigned long long* __restrict__ bkey,
                     unsigned* __restrict__ bstart,
                     unsigned* __restrict__ bcnt) {
    __shared__ unsigned cur[NBUCK];   // histogram -> cursor
    __shared__ unsigned wsum[16];
    const int t    = threadIdx.x;     // 0..1023
    const int lane = t & 63;
    const int wv   = t >> 6;          // 0..15

#pragma unroll
    for (int e = 0; e < 4; ++e) cur[t + e * 1024] = 0u;
    __syncthreads();

    for (int j = t; j < A_TOT; j += 1024)
        atomicAdd(&cur[(unsigned)(key[j] >> 52)], 1u);
    __syncthreads();

    // each thread owns buckets [4t, 4t+4)
    unsigned c0 = cur[4*t+0], c1 = cur[4*t+1], c2 = cur[4*t+2], c3 = cur[4*t+3];
    unsigned mysum = c0 + c1 + c2 + c3;

    // wave-level inclusive scan of per-thread sums
    unsigned incl = mysum;
#pragma unroll
    for (int off = 1; off < 64; off <<= 1) {
        unsigned v = __shfl_up(incl, off, 64);
        if (lane >= off) incl += v;
    }
    if (lane == 63) wsum[wv] = incl;
    __syncthreads();
    if (t == 0) {
        unsigned run = 0;
        for (int k = 0; k < 16; ++k) { unsigned v = wsum[k]; wsum[k] = run; run += v; }
    }
    __syncthreads();

    unsigned base = wsum[wv] + (incl - mysum);   // exclusive prefix of bucket 4t
    unsigned s0 = base, s1 = s0 + c0, s2 = s1 + c1, s3 = s2 + c2;

    ((uint4*)bstart)[t] = make_uint4(s0, s1, s2, s3);
    ((uint4*)bcnt)[t]   = make_uint4(c0, c1, c2, c3);

    cur[4*t+0] = s0; cur[4*t+1] = s1; cur[4*t+2] = s2; cur[4*t+3] = s3;
    __syncthreads();

    for (int j = t; j < A_TOT; j += 1024) {
        unsigned long long Ki = key[j];
        unsigned pos = atomicAdd(&cur[(unsigned)(Ki >> 52)], 1u);
        bkey[pos] = Ki;
    }
}

// ---------------- K3: wave-cooperative exact rank + scatter ------------------
// One 64-lane wave per bkey slot p; rank within bucket via ballot+popc.
__global__ void rankscatter_kernel(const unsigned long long* __restrict__ bkey,
                                   const unsigned* __restrict__ bstart,
                                   const unsigned* __restrict__ bcnt,
                                   const float4* __restrict__ roi,
                                   float4* __restrict__ sboxes,
                                   float* __restrict__ sareas) {
    int g = blockIdx.x * blockDim.x + threadIdx.x;
    int p = g >> 6;
    int lane = g & 63;
    if (p >= A_TOT) return;

    unsigned long long Ki = bkey[p];
    unsigned b = (unsigned)(Ki >> 52);
    unsigned start = bstart[b];
    if (start >= N_PRE) return;          // whole bucket past top-N_PRE
    unsigned cnt = bcnt[b];

    unsigned r = start;
    for (unsigned m = 0; m < cnt; m += 64) {
        unsigned mm = m + lane;
        bool lt = (mm < cnt) && (bkey[start + mm] < Ki);
        r += (unsigned)__popcll(__ballot(lt));
    }

    if (lane == 0 && r < N_PRE) {
        unsigned idx = (unsigned)Ki;
        float4 bx = roi[idx];
        sboxes[r] = bx;
        sareas[r] = __fmul_rn(__fadd_rn(__fsub_rn(bx.z, bx.x), 1.0f),
                              __fadd_rn(__fsub_rn(bx.w, bx.y), 1.0f));
    }
}

// ---------------- K4: diagonal pair-overlap marking --------------------------
// mark[i] = OR over z in [0, N_PRE-2-i] of IoU(b[z], b[z+i+1]) >= 0.7
__global__ void nms_kernel(const float4* __restrict__ sboxes,
                           const float* __restrict__ sareas,
                           unsigned* __restrict__ mark) {
    int wid  = (blockIdx.x * blockDim.x + threadIdx.x) >> 6;
    int lane = threadIdx.x & 63;
    if (wid >= N_PRE) return;
    const int i      = wid;
    const int npairs = N_PRE - 1 - i;   // z in [0, npairs)

    bool found = false;
    for (int base = 0; base < npairs; base += 64) {
        int z = base + lane;
        bool over = false;
        if (z < npairs) {
            float4 bz = sboxes[z];
            float4 bj = sboxes[z + i + 1];
            float az = sareas[z];
            float aj = sareas[z + i + 1];
            float xx1 = fmaxf(bz.x, bj.x);
            float yy1 = fmaxf(bz.y, bj.y);
            float xx2 = fminf(bz.z, bj.z);
            float yy2 = fminf(bz.w, bj.w);
            float w = fmaxf(0.0f, __fadd_rn(__fsub_rn(xx2, xx1), 1.0f));
            float h = fmaxf(0.0f, __fadd_rn(__fsub_rn(yy2, yy1), 1.0f));
            float inter = __fmul_rn(w, h);
            float denom = __fsub_rn(__fadd_rn(az, aj), inter);
            float ovr   = __fdiv_rn(inter, denom);
            over = (ovr >= NMS_T);
        }
        if (__any(over)) { found = true; break; }
    }
    if (lane == 0) mark[i] = found ? 1u : 0u;
}

// ---------------- K5: stable compaction + output (shfl scan) -----------------
__global__ __launch_bounds__(1024)
void output_kernel(const unsigned* __restrict__ mark,
                   const float4* __restrict__ sboxes,
                   float* __restrict__ out) {
    __shared__ int wsum[16];
    __shared__ int s_total;
    const int t    = threadIdx.x;     // 0..1023
    const int lane = t & 63;
    const int wv   = t >> 6;
    const int E = 12;                 // 1024*12 = 12288 >= 12000
    const int i0 = t * E;

    bool keep[E];
    int cnt = 0;
#pragma unroll
    for (int e = 0; e < E; ++e) {
        int i = i0 + e;
        bool k = (i < N_PRE) && (mark[i] == 0u);
        keep[e] = k;
        cnt += k ? 1 : 0;
    }

    // wave inclusive scan of cnt
    int incl = cnt;
#pragma unroll
    for (int off = 1; off < 64; off <<= 1) {
        int v = __shfl_up(incl, off, 64);
        if (lane >= off) incl += v;
    }
    if (lane == 63) wsum[wv] = incl;
    __syncthreads();
    if (t == 0) {
        int run = 0;
        for (int k = 0; k < 16; ++k) { int v = wsum[k]; wsum[k] = run; run += v; }
        s_total = run;
    }
    __syncthreads();

    int base = wsum[wv] + (incl - cnt);
    const int total = s_total;

    int pos = base;
#pragma unroll
    for (int e = 0; e < E; ++e) {
        if (keep[e] && pos < N_POST) {
            float4 b = sboxes[i0 + e];
            out[4*pos+0] = b.x;
            out[4*pos+1] = b.y;
            out[4*pos+2] = b.z;
            out[4*pos+3] = b.w;
            out[4*N_POST + pos] = 1.0f;
        }
        pos += keep[e] ? 1 : 0;
    }
    for (int p = t; p < N_POST; p += 1024) {
        if (p >= total) {
            out[4*p+0] = 0.0f; out[4*p+1] = 0.0f;
            out[4*p+2] = 0.0f; out[4*p+3] = 0.0f;
            out[4*N_POST + p] = 0.0f;
        }
    }
}

// ---------------- launch ------------------------------------------------------
extern "C" void kernel_launch(void* const* d_in, const int* in_sizes, int n_in,
                              void* d_out, int out_size, void* d_ws, size_t ws_size,
                              hipStream_t stream) {
    const float* anch = (const float*)d_in[0];   // (A,4)
    const float* cls  = (const float*)d_in[1];   // (1,A,2)
    const float* pred = (const float*)d_in[2];   // (1,A,4)
    float* out = (float*)d_out;                  // 8000 rois + 2000 kept

    char* ws = (char*)d_ws;
    float4*             roi    = (float4*)(ws + 0);                   // 298,800
    unsigned long long* key    = (unsigned long long*)(ws + 299008);  // 149,400
    unsigned long long* bkey   = (unsigned long long*)(ws + 448512);  // 149,400
    unsigned*           bstart = (unsigned*)(ws + 598016);            //  16,384
    unsigned*           bcnt   = (unsigned*)(ws + 614400);            //  16,384
    float4*             sboxes = (float4*)(ws + 630784);              // 192,000
    float*              sareas = (float*)(ws + 822784);               //  48,000
    unsigned*           mark   = (unsigned*)(ws + 870784);            //  48,000

    const int TB = 256;
    const int ablk = (A_TOT + TB - 1) / TB;            // 73
    const int rblk = (A_TOT * 64 + TB - 1) / TB;       // 4669

    decode_kernel<<<ablk, TB, 0, stream>>>(anch, cls, pred, roi, key);
    sortprep_kernel<<<1, 1024, 0, stream>>>(key, bkey, bstart, bcnt);
    rankscatter_kernel<<<rblk, TB, 0, stream>>>(bkey, bstart, bcnt, roi, sboxes, sareas);
    nms_kernel<<<(N_PRE * 64) / TB, TB, 0, stream>>>(sboxes, sareas, mark);
    output_kernel<<<1, 1024, 0, stream>>>(mark, sboxes, out);
}